// Round 1
// baseline (1489.401 us; speedup 1.0000x reference)
//
#include <hip/hip_runtime.h>

// ---------------------------------------------------------------------------
// MoE forward: gating MLP + 8 dense experts + gate-weighted combine.
// Strategy: everything matmul-shaped via mfma_f32_16x16x32_f16 (fp32 accum),
// fp16 chosen over bf16 for 8x mantissa margin vs the 1.04e-2 threshold.
// GEMM: m97-style 128x128 tile, BK=64, global_load_lds(16B) staging with
// XOR-swizzle applied as (inverse-swizzled global source, swizzled ds_read)
// per rule #21 (global_load_lds writes linearly).
// ---------------------------------------------------------------------------

#define DI __device__ __forceinline__

typedef _Float16 f16;
typedef _Float16 f16x8 __attribute__((ext_vector_type(8)));
typedef float f32x4 __attribute__((ext_vector_type(4)));

constexpr int BSZ  = 8192;
constexpr int IND  = 1024;
constexpr int HID  = 4096;
constexpr int OUTD = 1024;
constexpr int NE   = 8;
constexpr int HGD  = 2048;

// ---------------- fp32 -> fp16 vectorized convert (8 elems/thread) ---------
__global__ __launch_bounds__(256) void conv_f32_f16_kernel(
    const float* __restrict__ in, f16* __restrict__ out)
{
    size_t i = ((size_t)blockIdx.x * 256 + threadIdx.x) * 8;
    const float4* p = (const float4*)(in + i);
    float4 a = p[0], b = p[1];
    f16x8 v = {(f16)a.x, (f16)a.y, (f16)a.z, (f16)a.w,
               (f16)b.x, (f16)b.y, (f16)b.z, (f16)b.w};
    *(f16x8*)(out + i) = v;
}

// ------------- transpose + convert: W[K][N] f32 -> Wt[N][K] f16 ------------
__global__ __launch_bounds__(256) void transpose_f32_f16_kernel(
    const float* __restrict__ W, f16* __restrict__ Wt, int K, int N)
{
    __shared__ float t[64][65];          // +1 pad: conflict-free column reads
    int n0 = blockIdx.x * 64, k0 = blockIdx.y * 64;
    int tx = threadIdx.x & 63, ty = threadIdx.x >> 6;
#pragma unroll
    for (int i = 0; i < 16; i++) {
        int k = i * 4 + ty;
        t[k][tx] = W[(size_t)(k0 + k) * N + n0 + tx];   // coalesced 256B rows
    }
    __syncthreads();
#pragma unroll
    for (int i = 0; i < 16; i++) {
        int n = i * 4 + ty;
        Wt[(size_t)(n0 + n) * K + k0 + tx] = (f16)t[tx][n];  // coalesced 128B
    }
}

// ---------------- async global->LDS (16B per lane, wave-uniform dest) ------
DI void gload_lds16(const void* g, void* l)
{
    typedef const __attribute__((address_space(1))) unsigned int as1_t;
    typedef __attribute__((address_space(3))) unsigned int as3_t;
    __builtin_amdgcn_global_load_lds(
        (as1_t*)(unsigned long long)(__SIZE_TYPE__)g,
        (as3_t*)(unsigned int)(__SIZE_TYPE__)l,
        16, 0, 0);
}

// ---------------------------------------------------------------------------
// GEMM: C[M,N] = op(A[M,K] @ Bt[N,K]^T + bias[N])
//   RELU: v = max(v,0) after bias
//   GATE: v *= gate[row*NE]  (applied after bias/relu)
//   OUT_F16: store f16, else fp32 (ACCUM: read-modify-write)
// 128x128 tile, BK=64, 4 waves as 2x2, 4x4 frags of 16x16x32 MFMA per wave.
// LDS tiles [128 rows][64 k] f16 (128B rows), XOR swizzle byte^=((row&7)<<4)
// applied on the *global source* during staging and on ds_read addresses.
// ---------------------------------------------------------------------------
template <bool RELU, bool GATE, bool OUT_F16, bool ACCUM>
__global__ __launch_bounds__(256, 2) void gemm_f16_kernel(
    const f16* __restrict__ A, const f16* __restrict__ Bt,
    const float* __restrict__ bias, const float* __restrict__ gate,
    void* __restrict__ Cptr, int M, int N, int K)
{
    constexpr int BK = 64;
    __shared__ __align__(16) f16 sA[128 * BK];
    __shared__ __align__(16) f16 sB[128 * BK];
    const int tid  = threadIdx.x;
    const int wid  = tid >> 6, lane = tid & 63;
    const size_t bm = (size_t)blockIdx.y * 128;
    const size_t bn = (size_t)blockIdx.x * 128;

    f32x4 acc[4][4] = {};

    // staging geometry: chunk c covers LDS bytes [c*1024, c*1024+1024)
    // = rows [c*8, c*8+8) of the tile; lane l -> row c*8+(l>>3),
    // within-row byte (l&7)*16; source column pre-XORed so that the
    // swizzled ds_read below sees logical data.
    int rr[4], oo[4];
#pragma unroll
    for (int i = 0; i < 4; i++) {
        int c = wid * 4 + i;
        rr[i] = c * 8 + (lane >> 3);
        oo[i] = ((((lane & 7) * 16) ^ ((rr[i] & 7) << 4)) >> 1);  // elem offset
    }
    const f16* Abase = A + bm * (size_t)K;
    const f16* Bbase = Bt + bn * (size_t)K;

    for (int kt = 0; kt < K; kt += BK) {
        __syncthreads();   // protect LDS against previous iteration's reads
#pragma unroll
        for (int i = 0; i < 4; i++) {
            int c = wid * 4 + i;
            gload_lds16(Abase + (size_t)rr[i] * K + kt + oo[i], (char*)sA + c * 1024);
            gload_lds16(Bbase + (size_t)rr[i] * K + kt + oo[i], (char*)sB + c * 1024);
        }
        __syncthreads();   // drains vmcnt: staged data visible

#pragma unroll
        for (int kk = 0; kk < BK; kk += 32) {
            f16x8 av[4], bv[4];
            const int kb = (kk + ((lane >> 4) * 8)) * 2;  // byte offset in row
#pragma unroll
            for (int f = 0; f < 4; f++) {
                int Ra = ((wid >> 1) * 64) + f * 16 + (lane & 15);
                int Rb = ((wid & 1) * 64) + f * 16 + (lane & 15);
                av[f] = *(const f16x8*)((const char*)sA + Ra * 128 + (kb ^ ((Ra & 7) << 4)));
                bv[f] = *(const f16x8*)((const char*)sB + Rb * 128 + (kb ^ ((Rb & 7) << 4)));
            }
#pragma unroll
            for (int fm = 0; fm < 4; fm++)
#pragma unroll
                for (int fn = 0; fn < 4; fn++)
                    acc[fm][fn] = __builtin_amdgcn_mfma_f32_16x16x32_f16(
                        av[fm], bv[fn], acc[fm][fn], 0, 0, 0);
        }
    }

    // epilogue: C/D layout col=lane&15, row=(lane>>4)*4+reg  [m89-verified]
    const int wm = (wid >> 1) * 64, wn = (wid & 1) * 64;
    const int c0 = lane & 15, r0 = (lane >> 4) * 4;
#pragma unroll
    for (int fm = 0; fm < 4; fm++) {
#pragma unroll
        for (int r = 0; r < 4; r++) {
            const size_t row = bm + wm + fm * 16 + r0 + r;
            float g = 1.0f;
            if constexpr (GATE) g = gate[row * NE];
#pragma unroll
            for (int fn = 0; fn < 4; fn++) {
                const size_t col = bn + wn + fn * 16 + c0;
                float v = acc[fm][fn][r] + bias[col];
                if constexpr (RELU) v = fmaxf(v, 0.0f);
                if constexpr (GATE) v *= g;
                if constexpr (OUT_F16) {
                    ((f16*)Cptr)[row * (size_t)N + col] = (f16)v;
                } else {
                    float* p = (float*)Cptr + row * (size_t)N + col;
                    *p = ACCUM ? (*p + v) : v;
                }
            }
        }
    }
}

// --------- gating head: logits = gh@gw2 + gb2, softmax -> gates fp32 -------
// one wave per batch row; lane-strided K, shuffle reduce.
__global__ __launch_bounds__(256) void gate_softmax_kernel(
    const f16* __restrict__ gh, const float* __restrict__ gw2,
    const float* __restrict__ gb2, float* __restrict__ gates)
{
    const int row  = blockIdx.x * 4 + (threadIdx.x >> 6);
    const int lane = threadIdx.x & 63;
    const f16* r = gh + (size_t)row * HGD;
    float acc[NE] = {};
    for (int k = lane; k < HGD; k += 64) {
        float h = (float)r[k];
        const float* w = gw2 + (size_t)k * NE;
#pragma unroll
        for (int e = 0; e < NE; e++) acc[e] = fmaf(h, w[e], acc[e]);
    }
#pragma unroll
    for (int off = 32; off > 0; off >>= 1)
#pragma unroll
        for (int e = 0; e < NE; e++) acc[e] += __shfl_down(acc[e], off, 64);
    if (lane == 0) {
        float l[NE], m = -1e30f;
#pragma unroll
        for (int e = 0; e < NE; e++) { l[e] = acc[e] + gb2[e]; m = fmaxf(m, l[e]); }
        float s = 0.f;
#pragma unroll
        for (int e = 0; e < NE; e++) { l[e] = expf(l[e] - m); s += l[e]; }
        float inv = 1.0f / s;
#pragma unroll
        for (int e = 0; e < NE; e++) gates[(size_t)row * NE + e] = l[e] * inv;
    }
}

// ---------------------------------------------------------------------------
extern "C" void kernel_launch(void* const* d_in, const int* in_sizes, int n_in,
                              void* d_out, int out_size, void* d_ws, size_t ws_size,
                              hipStream_t stream)
{
    const float* x   = (const float*)d_in[0];
    const float* gw1 = (const float*)d_in[1];
    const float* gb1 = (const float*)d_in[2];
    const float* gw2 = (const float*)d_in[3];
    const float* gb2 = (const float*)d_in[4];
    const float* ew1 = (const float*)d_in[5];
    const float* eb1 = (const float*)d_in[6];
    const float* ew2 = (const float*)d_in[7];
    const float* eb2 = (const float*)d_in[8];
    float* out = (float*)d_out;

    // ws layout (88.5 MB total):
    //   gates : BSZ*NE fp32              (256 KB)
    //   x16   : BSZ*IND f16              (16 MB)
    //   wbuf  : max weight transpose, 4M f16 (8 MB)   [reused 17x]
    //   hbuf  : BSZ*HID f16              (64 MB)      [gh (32MB) aliases it]
    char* ws = (char*)d_ws;
    float* gates = (float*)ws;
    f16* x16  = (f16*)(ws + (256 << 10));
    f16* wbuf = x16 + (size_t)BSZ * IND;
    f16* hbuf = wbuf + (size_t)HID * IND;
    f16* gh   = hbuf;  // alias: gh fully consumed before first expert GEMM

    // 1) x -> fp16
    conv_f32_f16_kernel<<<(BSZ * IND) / (256 * 8), 256, 0, stream>>>(x, x16);

    // 2) gating GEMM1: gh = relu(x @ gw1 + gb1)
    transpose_f32_f16_kernel<<<dim3(HGD / 64, IND / 64), 256, 0, stream>>>(gw1, wbuf, IND, HGD);
    gemm_f16_kernel<true, false, true, false>
        <<<dim3(HGD / 128, BSZ / 128), 256, 0, stream>>>(
            x16, wbuf, gb1, nullptr, gh, BSZ, HGD, IND);

    // 3) gating head + softmax -> gates
    gate_softmax_kernel<<<BSZ / 4, 256, 0, stream>>>(gh, gw2, gb2, gates);

    // 4) experts
    for (int e = 0; e < NE; e++) {
        // h = relu(x @ ew1[e] + eb1[e])
        transpose_f32_f16_kernel<<<dim3(HID / 64, IND / 64), 256, 0, stream>>>(
            ew1 + (size_t)e * IND * HID, wbuf, IND, HID);
        gemm_f16_kernel<true, false, true, false>
            <<<dim3(HID / 128, BSZ / 128), 256, 0, stream>>>(
                x16, wbuf, eb1 + (size_t)e * HID, nullptr, hbuf, BSZ, HID, IND);

        // out (+)= gates[:,e] * (h @ ew2[e] + eb2[e])
        transpose_f32_f16_kernel<<<dim3(OUTD / 64, HID / 64), 256, 0, stream>>>(
            ew2 + (size_t)e * HID * OUTD, wbuf, HID, OUTD);
        if (e == 0)
            gemm_f16_kernel<false, true, false, false>
                <<<dim3(OUTD / 128, BSZ / 128), 256, 0, stream>>>(
                    hbuf, wbuf, eb2 + (size_t)e * OUTD, gates + e, out, BSZ, OUTD, HID);
        else
            gemm_f16_kernel<false, true, false, true>
                <<<dim3(OUTD / 128, BSZ / 128), 256, 0, stream>>>(
                    hbuf, wbuf, eb2 + (size_t)e * OUTD, gates + e, out, BSZ, OUTD, HID);
    }
}

// Round 2
// 1428.707 us; speedup vs baseline: 1.0425x; 1.0425x over previous
//
#include <hip/hip_runtime.h>

// ---------------------------------------------------------------------------
// MoE forward: gating MLP + 8 dense experts + gate-weighted combine.
// All matmuls via mfma_f32_16x16x32_f16 (fp32 accum).
// GEMM: 256xBN 8-phase deep-pipelined template (T2 swizzle + T3/T4 counted
// vmcnt + T5 setprio + T1 XCD swizzle). BM=256, BK=64, 8 waves (2M x 4N),
// double-buffered LDS; B-fragments preloaded to registers in phases 1-2 so
// the B LDS region frees early; stages never drain vmcnt to 0 in-loop.
// ---------------------------------------------------------------------------

#define DI __device__ __forceinline__

typedef _Float16 f16;
typedef _Float16 f16x8 __attribute__((ext_vector_type(8)));
typedef float f32x4 __attribute__((ext_vector_type(4)));

constexpr int BSZ  = 8192;
constexpr int IND  = 1024;
constexpr int HID  = 4096;
constexpr int OUTD = 1024;
constexpr int NE   = 8;
constexpr int HGD  = 2048;

// ---------------- fp32 -> fp16 vectorized convert (8 elems/thread) ---------
__global__ __launch_bounds__(256) void conv_f32_f16_kernel(
    const float* __restrict__ in, f16* __restrict__ out)
{
    size_t i = ((size_t)blockIdx.x * 256 + threadIdx.x) * 8;
    const float4* p = (const float4*)(in + i);
    float4 a = p[0], b = p[1];
    f16x8 v = {(f16)a.x, (f16)a.y, (f16)a.z, (f16)a.w,
               (f16)b.x, (f16)b.y, (f16)b.z, (f16)b.w};
    *(f16x8*)(out + i) = v;
}

// ------------- transpose + convert: W[K][N] f32 -> Wt[N][K] f16 ------------
__global__ __launch_bounds__(256) void transpose_f32_f16_kernel(
    const float* __restrict__ W, f16* __restrict__ Wt, int K, int N)
{
    __shared__ float t[64][65];
    int n0 = blockIdx.x * 64, k0 = blockIdx.y * 64;
    int tx = threadIdx.x & 63, ty = threadIdx.x >> 6;
#pragma unroll
    for (int i = 0; i < 16; i++) {
        int k = i * 4 + ty;
        t[k][tx] = W[(size_t)(k0 + k) * N + n0 + tx];
    }
    __syncthreads();
#pragma unroll
    for (int i = 0; i < 16; i++) {
        int n = i * 4 + ty;
        Wt[(size_t)(n0 + n) * K + k0 + tx] = (f16)t[tx][n];
    }
}

// ---------------- async global->LDS (16B per lane, wave-uniform dest) ------
DI void gload_lds16(const void* g, void* l)
{
    typedef const __attribute__((address_space(1))) unsigned int as1_t;
    typedef __attribute__((address_space(3))) unsigned int as3_t;
    __builtin_amdgcn_global_load_lds(
        (as1_t*)(unsigned long long)(__SIZE_TYPE__)g,
        (as3_t*)(unsigned int)(__SIZE_TYPE__)l,
        16, 0, 0);
}

// ---------------------------------------------------------------------------
// 8-phase GEMM: C[M,N] = op(A[M,K] @ Bt[N,K]^T + bias[N])
// Schedule (iteration i computes tile t=2i from buf0, t+1 from buf1):
//  P1: ldA(b0,mh0,k0)+ldB-pre(b0,k0) | stage A(t+1)->buf1 (4 calls)
//  P2: ldA(b0,mh0,k1)+ldB-pre(b0,k1) | -
//  P3: ldA(b0,mh1,k0)                | stage B(t+2) q0,q1 -> buf0
//  P4: ldA(b0,mh1,k1)                | stage B(t+2) q2,q3 ; vmcnt(4|2)
//  P5..P8: same on buf1, staging A(t+2)->buf0 (P5), B(t+3)->buf1 (P7,P8);
//          vmcnt(4|2) at P8.  Final iteration: vmcnt(0) at P4/P8.
// Every stage target's last LDS read is >=1 barrier-phase earlier (B region
// is only read during the tile's first two phases thanks to reg-preload).
// ---------------------------------------------------------------------------

#define PH(BUF, MH, KS, PRE, STAGE, VM)                                        \
  {                                                                            \
    f16x8 av0 = ldA(BUF, 0, MH, KS);                                           \
    f16x8 av1 = ldA(BUF, 1, MH, KS);                                           \
    f16x8 av2 = ldA(BUF, 2, MH, KS);                                           \
    f16x8 av3 = ldA(BUF, 3, MH, KS);                                           \
    if constexpr ((PRE) >= 0) {                                                \
      _Pragma("unroll")                                                        \
      for (int n = 0; n < NF; n++) breg[n][KS] = ldB(BUF, n, KS);              \
    }                                                                          \
    STAGE                                                                      \
    __builtin_amdgcn_sched_barrier(0);                                         \
    __builtin_amdgcn_s_barrier();                                              \
    asm volatile("s_waitcnt lgkmcnt(0)" ::: "memory");                         \
    __builtin_amdgcn_sched_barrier(0);                                         \
    __builtin_amdgcn_s_setprio(1);                                             \
    _Pragma("unroll")                                                          \
    for (int n = 0; n < NF; n++) {                                             \
      acc[(MH)*4+0][n] = __builtin_amdgcn_mfma_f32_16x16x32_f16(av0, breg[n][KS], acc[(MH)*4+0][n], 0, 0, 0); \
      acc[(MH)*4+1][n] = __builtin_amdgcn_mfma_f32_16x16x32_f16(av1, breg[n][KS], acc[(MH)*4+1][n], 0, 0, 0); \
      acc[(MH)*4+2][n] = __builtin_amdgcn_mfma_f32_16x16x32_f16(av2, breg[n][KS], acc[(MH)*4+2][n], 0, 0, 0); \
      acc[(MH)*4+3][n] = __builtin_amdgcn_mfma_f32_16x16x32_f16(av3, breg[n][KS], acc[(MH)*4+3][n], 0, 0, 0); \
    }                                                                          \
    __builtin_amdgcn_s_setprio(0);                                             \
    VM                                                                         \
    __builtin_amdgcn_sched_barrier(0);                                         \
    __builtin_amdgcn_s_barrier();                                              \
    asm volatile("" ::: "memory");                                             \
  }

#define VMSTEP                                                                 \
  { if (i + 1 == NI) { asm volatile("s_waitcnt vmcnt(0)"); }                   \
    else if constexpr (BN == 256) { asm volatile("s_waitcnt vmcnt(4)"); }      \
    else { asm volatile("s_waitcnt vmcnt(2)"); } }

template <int BN, bool RELU, bool GATE, bool OUT_F16, bool ACCUM>
__global__ __launch_bounds__(512, 2) void gemm8p_kernel(
    const f16* __restrict__ A, const f16* __restrict__ Bt,
    const float* __restrict__ bias, const float* __restrict__ gate,
    void* __restrict__ Cptr, int M, int N, int K)
{
    constexpr int BM = 256, BK = 64;
    constexpr int NF  = BN / 64;             // n-frags per wave
    constexpr int NBC = (BN * BK * 2) / 8192; // B stage calls per tile (4|2)
    __shared__ __align__(16) f16 sA[2][BM * BK];
    __shared__ __align__(16) f16 sB[2][BN * BK];

    const int tid = threadIdx.x, wid = tid >> 6, lane = tid & 63;
    const int wm = wid >> 2, wn = wid & 3;

    // bijective XCD swizzle (all grids here are multiples of 8)
    const int nwg = gridDim.x;
    const int bid = blockIdx.x;
    const int wg  = (bid & 7) * (nwg >> 3) + (bid >> 3);
    const int gx  = N / BN;
    const size_t bm = (size_t)(wg / gx) * BM;
    const size_t bn = (size_t)(wg % gx) * BN;

    f32x4 acc[8][NF] = {};
    f16x8 breg[NF][2];

    // staging geometry: one call = 8KB = 64 rows; thread -> row wid*8+(lane>>3),
    // in-row byte (lane&7)*16; source col pre-XOR'd (rule #21) so swizzled
    // ds_read sees logical data; LDS dest linear (wave-uniform base + lane*16).
    const int srow = (wid << 3) + (lane >> 3);
    const int scol = ((((lane & 7) << 4) ^ (((lane >> 3) & 7) << 4)) >> 1);
    const f16* Ab = A  + (bm + srow) * (size_t)K + scol;
    const f16* Bb = Bt + (bn + srow) * (size_t)K + scol;
    char* sAb = (char*)&sA[0][0] + wid * 1024;
    char* sBb = (char*)&sB[0][0] + wid * 1024;

    auto stA = [&](int b, int q, int t) {
        gload_lds16(Ab + (size_t)q * 64 * K + t * BK,
                    sAb + b * (BM * BK * 2) + q * 8192);
    };
    auto stB = [&](int b, int q, int t) {
        gload_lds16(Bb + (size_t)q * 64 * K + t * BK,
                    sBb + b * (BN * BK * 2) + q * 8192);
    };
    auto ldA = [&](int b, int f, int mh, int ks) -> f16x8 {
        int r  = wm * 128 + mh * 64 + f * 16 + (lane & 15);
        int kb = (((ks * 32) + ((lane >> 4) << 3)) << 1) ^ ((r & 7) << 4);
        return *(const f16x8*)((const char*)&sA[b][0] + r * 128 + kb);
    };
    auto ldB = [&](int b, int n, int ks) -> f16x8 {
        int r  = wn * (BN / 4) + n * 16 + (lane & 15);
        int kb = (((ks * 32) + ((lane >> 4) << 3)) << 1) ^ ((r & 7) << 4);
        return *(const f16x8*)((const char*)&sB[b][0] + r * 128 + kb);
    };

    const int NT = K / BK, NI = NT / 2;

    // prologue: t0 A+B, t1 B; wait everything except t1's B
#pragma unroll
    for (int q = 0; q < 4; q++) stA(0, q, 0);
#pragma unroll
    for (int q = 0; q < NBC; q++) stB(0, q, 0);
#pragma unroll
    for (int q = 0; q < NBC; q++) stB(1, q, 1);
    if constexpr (NBC == 4) { asm volatile("s_waitcnt vmcnt(4)"); }
    else                    { asm volatile("s_waitcnt vmcnt(2)"); }
    __builtin_amdgcn_s_barrier();
    asm volatile("" ::: "memory");

    for (int i = 0; i < NI; ++i) {
        const int t = 2 * i;
        const bool pf = (i + 1 < NI);
        // P1
        PH(0, 0, 0, 0,
           { stA(1,0,t+1); stA(1,1,t+1); stA(1,2,t+1); stA(1,3,t+1); }, {})
        // P2
        PH(0, 0, 1, 1, {}, {})
        // P3
        PH(0, 1, 0, -1,
           { if (pf) { stB(0,0,t+2); stB(0,1,t+2); } }, {})
        // P4
        PH(0, 1, 1, -1,
           { if (pf) { if constexpr (NBC == 4) { stB(0,2,t+2); stB(0,3,t+2); } } },
           VMSTEP)
        // P5
        PH(1, 0, 0, 0,
           { if (pf) { stA(0,0,t+2); stA(0,1,t+2); stA(0,2,t+2); stA(0,3,t+2); } }, {})
        // P6
        PH(1, 0, 1, 1, {}, {})
        // P7
        PH(1, 1, 0, -1,
           { if (pf) { stB(1,0,t+3); stB(1,1,t+3); } }, {})
        // P8
        PH(1, 1, 1, -1,
           { if (pf) { if constexpr (NBC == 4) { stB(1,2,t+3); stB(1,3,t+3); } } },
           VMSTEP)
    }

    // epilogue: C/D layout col=lane&15, row=(lane>>4)*4+reg  [m89-verified]
    const size_t row0 = bm + (size_t)wm * 128;
    const int col0 = (int)bn + wn * (BN / 4);
    const int c0 = lane & 15, r0 = (lane >> 4) * 4;
#pragma unroll
    for (int fm = 0; fm < 8; fm++) {
#pragma unroll
        for (int r = 0; r < 4; r++) {
            const size_t row = row0 + fm * 16 + r0 + r;
            float g = 1.0f;
            if constexpr (GATE) g = gate[row * NE];
#pragma unroll
            for (int n = 0; n < NF; n++) {
                const size_t col = (size_t)col0 + n * 16 + c0;
                float v = acc[fm][n][r] + bias[col];
                if constexpr (RELU) v = fmaxf(v, 0.0f);
                if constexpr (GATE) v *= g;
                if constexpr (OUT_F16) {
                    ((f16*)Cptr)[row * (size_t)N + col] = (f16)v;
                } else {
                    float* p = (float*)Cptr + row * (size_t)N + col;
                    *p = ACCUM ? (*p + v) : v;
                }
            }
        }
    }
}

// --------- gating head: logits = gh@gw2 + gb2, softmax -> gates fp32 -------
__global__ __launch_bounds__(256) void gate_softmax_kernel(
    const f16* __restrict__ gh, const float* __restrict__ gw2,
    const float* __restrict__ gb2, float* __restrict__ gates)
{
    const int row  = blockIdx.x * 4 + (threadIdx.x >> 6);
    const int lane = threadIdx.x & 63;
    const f16* r = gh + (size_t)row * HGD;
    float acc[NE] = {};
    for (int k = lane; k < HGD; k += 64) {
        float h = (float)r[k];
        const float* w = gw2 + (size_t)k * NE;
#pragma unroll
        for (int e = 0; e < NE; e++) acc[e] = fmaf(h, w[e], acc[e]);
    }
#pragma unroll
    for (int off = 32; off > 0; off >>= 1)
#pragma unroll
        for (int e = 0; e < NE; e++) acc[e] += __shfl_down(acc[e], off, 64);
    if (lane == 0) {
        float l[NE], m = -1e30f;
#pragma unroll
        for (int e = 0; e < NE; e++) { l[e] = acc[e] + gb2[e]; m = fmaxf(m, l[e]); }
        float s = 0.f;
#pragma unroll
        for (int e = 0; e < NE; e++) { l[e] = expf(l[e] - m); s += l[e]; }
        float inv = 1.0f / s;
#pragma unroll
        for (int e = 0; e < NE; e++) gates[(size_t)row * NE + e] = l[e] * inv;
    }
}

// ---------------------------------------------------------------------------
extern "C" void kernel_launch(void* const* d_in, const int* in_sizes, int n_in,
                              void* d_out, int out_size, void* d_ws, size_t ws_size,
                              hipStream_t stream)
{
    const float* x   = (const float*)d_in[0];
    const float* gw1 = (const float*)d_in[1];
    const float* gb1 = (const float*)d_in[2];
    const float* gw2 = (const float*)d_in[3];
    const float* gb2 = (const float*)d_in[4];
    const float* ew1 = (const float*)d_in[5];
    const float* eb1 = (const float*)d_in[6];
    const float* ew2 = (const float*)d_in[7];
    const float* eb2 = (const float*)d_in[8];
    float* out = (float*)d_out;

    // ws layout: gates(256KB) | x16(16MB) | wbuf(8MB) | hbuf(64MB, gh aliases)
    char* ws = (char*)d_ws;
    float* gates = (float*)ws;
    f16* x16  = (f16*)(ws + (256 << 10));
    f16* wbuf = x16 + (size_t)BSZ * IND;
    f16* hbuf = wbuf + (size_t)HID * IND;
    f16* gh   = hbuf;  // alias: gh fully consumed before first expert GEMM

    // 1) x -> fp16
    conv_f32_f16_kernel<<<(BSZ * IND) / (256 * 8), 256, 0, stream>>>(x, x16);

    // 2) gating GEMM1: gh = relu(x @ gw1 + gb1)   [M=8192,N=2048,K=1024]
    transpose_f32_f16_kernel<<<dim3(HGD / 64, IND / 64), 256, 0, stream>>>(gw1, wbuf, IND, HGD);
    gemm8p_kernel<256, true, false, true, false>
        <<<(HGD / 256) * (BSZ / 256), 512, 0, stream>>>(
            x16, wbuf, gb1, nullptr, gh, BSZ, HGD, IND);

    // 3) gating head + softmax -> gates
    gate_softmax_kernel<<<BSZ / 4, 256, 0, stream>>>(gh, gw2, gb2, gates);

    // 4) experts
    for (int e = 0; e < NE; e++) {
        // h = relu(x @ ew1[e] + eb1[e])   [M=8192,N=4096,K=1024]
        transpose_f32_f16_kernel<<<dim3(HID / 64, IND / 64), 256, 0, stream>>>(
            ew1 + (size_t)e * IND * HID, wbuf, IND, HID);
        gemm8p_kernel<256, true, false, true, false>
            <<<(HID / 256) * (BSZ / 256), 512, 0, stream>>>(
                x16, wbuf, eb1 + (size_t)e * HID, nullptr, hbuf, BSZ, HID, IND);

        // out (+)= gates[:,e] * (h @ ew2[e] + eb2[e])   [M=8192,N=1024,K=4096]
        transpose_f32_f16_kernel<<<dim3(OUTD / 64, HID / 64), 256, 0, stream>>>(
            ew2 + (size_t)e * HID * OUTD, wbuf, HID, OUTD);
        if (e == 0)
            gemm8p_kernel<128, false, true, false, false>
                <<<(OUTD / 128) * (BSZ / 256), 512, 0, stream>>>(
                    hbuf, wbuf, eb2 + (size_t)e * OUTD, gates + e, out, BSZ, OUTD, HID);
        else
            gemm8p_kernel<128, false, true, false, true>
                <<<(OUTD / 128) * (BSZ / 256), 512, 0, stream>>>(
                    hbuf, wbuf, eb2 + (size_t)e * OUTD, gates + e, out, BSZ, OUTD, HID);
    }
}